// Round 17
// baseline (77.104 us; speedup 1.0000x reference)
//
#include <hip/hip_runtime.h>
#include <hip/hip_bf16.h>

// HFOnlyAttn MFMA v14: multi-tile pipelined waves + LDS-staged X loads.
// Little's-law fix: in-flight load bytes live in LDS (global_load_lds, zero
// VGPR) and overlap compute via prefetch-next-tile. Each wave: 4 tiles of
// 16 px; per tile: wait loads -> ds_read X -> convert -> issue prefetch(t+1)
// -> v10 compute (heads, shuffle relayout, residual-from-Xf, stores).
// LDS 12KB/wave (48KB/block) -> 3 blocks/CU; all 512 blocks resident.
// mfma_f32_16x16x32_bf16:  A: lane l -> row=l&15, k=(l>>4)*8+{0..7}
//                          B: lane l -> col=l&15, k=(l>>4)*8+{0..7}
//                          C: lane l -> col=l&15, row=(l>>4)*4+reg
// Relayout (v4/v10-verified): proj-B-frag(sp) lane(g,c) elem e = ych
// sp*32+g*8+e; holder lane ((g&1)*2+(e>>2))*16+c, head sp*2+(g>>1), reg e&3.
// Residual: channel b*64+m*16+g*4+j of pixel c lives in Xf[b][m>>1],
// element (g&1)*4+j, on lane ((m&1)*2+(g>>1))*16+c.
// LDS X layout (v8-verified): lds32[ch*16 + px], gload instr i: lane l reads
// 16B of channel i*16+(l>>2), px group (l&3)*4; dest = base + i*1024 + l*16.

typedef __attribute__((ext_vector_type(8))) short bf16x8;
typedef __attribute__((ext_vector_type(4))) float f32x4;

constexpr int kHW = 16384;
constexpr int kC = 192;

__device__ __forceinline__ short f2bf(float f) {
  return (short)__bfloat16_as_ushort(__float2bfloat16(f));
}

// kernel0: pack Wqkv^T/Wproj^T A-fragments into ws (24 + 8 frags x 1024B).
__global__ void pack_weights(const float* __restrict__ Wqkv,
                             const float* __restrict__ Wproj,
                             unsigned char* __restrict__ wsc) {
  const int tid = threadIdx.x;
  const int wid = tid >> 6;
  const int l = tid & 63;
  const int c = l & 15;
  const int g = l >> 4;
  for (int f = wid; f < 24; f += 4) {
    const int m = f >> 1, s = f & 1;
    const int row = m * 16 + c;
    const int k0 = s * 32 + g * 8;
    bf16x8 wf;
#pragma unroll
    for (int j = 0; j < 8; ++j) wf[j] = f2bf(Wqkv[(k0 + j) * 192 + row]);
    *(bf16x8*)(wsc + f * 1024 + l * 16) = wf;
  }
  for (int f = wid; f < 8; f += 4) {
    const int m = f >> 1, s = f & 1;
    const int row = m * 16 + c;
    const int k0 = s * 32 + g * 8;
    bf16x8 wf;
#pragma unroll
    for (int j = 0; j < 8; ++j) wf[j] = f2bf(Wproj[(k0 + j) * 64 + row]);
    *(bf16x8*)(wsc + 24576 + f * 1024 + l * 16) = wf;
  }
}

// One head: q,k MFMAs -> 3x3 softmax -> v MFMAs -> y packs (3 uint2).
template <int H>
__device__ __forceinline__ void head_compute(const bf16x8* __restrict__ wp,
                                             int l, const bf16x8 (&Xf)[3][2],
                                             uint2 (&pk)[3]) {
  const f32x4 zz = {0.f, 0.f, 0.f, 0.f};
  const bf16x8 qA0 = wp[(H * 2 + 0) * 64 + l];
  const bf16x8 qA1 = wp[(H * 2 + 1) * 64 + l];
  const bf16x8 kA0 = wp[((4 + H) * 2 + 0) * 64 + l];
  const bf16x8 kA1 = wp[((4 + H) * 2 + 1) * 64 + l];
  f32x4 q[3], k[3];
#pragma unroll
  for (int b = 0; b < 3; ++b) {
    q[b] = __builtin_amdgcn_mfma_f32_16x16x32_bf16(qA0, Xf[b][0], zz, 0, 0, 0);
    q[b] = __builtin_amdgcn_mfma_f32_16x16x32_bf16(qA1, Xf[b][1], q[b], 0, 0, 0);
    k[b] = __builtin_amdgcn_mfma_f32_16x16x32_bf16(kA0, Xf[b][0], zz, 0, 0, 0);
    k[b] = __builtin_amdgcn_mfma_f32_16x16x32_bf16(kA1, Xf[b][1], k[b], 0, 0, 0);
  }
  float P[3][3];
#pragma unroll
  for (int r1 = 0; r1 < 3; ++r1) {
    float sc[3];
#pragma unroll
    for (int r2 = 0; r2 < 3; ++r2) {
      float d = q[r1][0] * k[r2][0] + q[r1][1] * k[r2][1] +
                q[r1][2] * k[r2][2] + q[r1][3] * k[r2][3];
      d += __shfl_xor(d, 16);
      d += __shfl_xor(d, 32);
      sc[r2] = d * 0.25f;
    }
    const float mx = fmaxf(sc[0], fmaxf(sc[1], sc[2]));
    const float e0 = __expf(sc[0] - mx);
    const float e1 = __expf(sc[1] - mx);
    const float e2 = __expf(sc[2] - mx);
    const float inv = 1.f / (e0 + e1 + e2);
    P[r1][0] = e0 * inv;
    P[r1][1] = e1 * inv;
    P[r1][2] = e2 * inv;
  }
  const bf16x8 vA0 = wp[((8 + H) * 2 + 0) * 64 + l];
  const bf16x8 vA1 = wp[((8 + H) * 2 + 1) * 64 + l];
  f32x4 v[3];
#pragma unroll
  for (int b = 0; b < 3; ++b) {
    v[b] = __builtin_amdgcn_mfma_f32_16x16x32_bf16(vA0, Xf[b][0], zz, 0, 0, 0);
    v[b] = __builtin_amdgcn_mfma_f32_16x16x32_bf16(vA1, Xf[b][1], v[b], 0, 0, 0);
  }
#pragma unroll
  for (int r1 = 0; r1 < 3; ++r1) {
    f32x4 y = P[r1][0] * v[0] + P[r1][1] * v[1] + P[r1][2] * v[2];
    uint2 p;
    p.x = (unsigned)(unsigned short)f2bf(y[0]) |
          ((unsigned)(unsigned short)f2bf(y[1]) << 16);
    p.y = (unsigned)(unsigned short)f2bf(y[2]) |
          ((unsigned)(unsigned short)f2bf(y[3]) << 16);
    pk[r1] = p;
  }
}

// Build proj-B-frag for K-step sp from the packs of heads (2sp, 2sp+1).
__device__ __forceinline__ bf16x8 build_frag(uint2 pkA, uint2 pkB, int srcA,
                                             bool hi) {
  uint2 a0, a1, b0, b1;
  a0.x = (unsigned)__shfl((int)pkA.x, srcA, 64);
  a0.y = (unsigned)__shfl((int)pkA.y, srcA, 64);
  a1.x = (unsigned)__shfl((int)pkB.x, srcA, 64);
  a1.y = (unsigned)__shfl((int)pkB.y, srcA, 64);
  const int srcB = srcA + 16;
  b0.x = (unsigned)__shfl((int)pkA.x, srcB, 64);
  b0.y = (unsigned)__shfl((int)pkA.y, srcB, 64);
  b1.x = (unsigned)__shfl((int)pkB.x, srcB, 64);
  b1.y = (unsigned)__shfl((int)pkB.y, srcB, 64);
  const uint2 lo = hi ? a1 : a0;
  const uint2 hi2 = hi ? b1 : b0;
  union {
    unsigned u[4];
    bf16x8 v;
  } r;
  r.u[0] = lo.x;
  r.u[1] = lo.y;
  r.u[2] = hi2.x;
  r.u[3] = hi2.y;
  return r.v;
}

__global__ __launch_bounds__(256, 3) void hfattn_mfma14(
    const float* __restrict__ hf,
    const unsigned char* __restrict__ wfr,  // packed weight frags (32KB)
    const float* __restrict__ bproj,
    const float* __restrict__ rscale,
    float* __restrict__ out) {
  // LDS: per-wave 12KB X staging buffer (fp32 [192ch][16px]).
  __shared__ char smem[49152];

  const int tid = threadIdx.x;
  const int wid = tid >> 6;
  const int l = tid & 63;
  const int c = l & 15;  // MFMA col (pixel slot)
  const int g = l >> 4;  // 4-lane group

  char* const wbase = smem + wid * 12288;
  const f32x4 zz = {0.f, 0.f, 0.f, 0.f};
  const bf16x8* const wp = (const bf16x8*)wfr;

  const int px0 = blockIdx.x * 256 + wid * 64;  // wave's first pixel (4 tiles)
  const int b8 = px0 >> 14;
  const int blkBase = b8 * (kC * kHW);
  const int hwW = px0 & (kHW - 1);

  // gload source: lane l covers channel (l>>2) of each 16-ch group, px group
  // (l&3)*4 within the tile.
  const float* const srcB = hf + blkBase + (l >> 2) * kHW + hwW + (l & 3) * 4;

  const float rv = rscale[0];
  float bias_[4][4];
#pragma unroll
  for (int m = 0; m < 4; ++m) {
    const float4 bj = *(const float4*)(bproj + m * 16 + g * 4);
    bias_[m][0] = bj.x;
    bias_[m][1] = bj.y;
    bias_[m][2] = bj.z;
    bias_[m][3] = bj.w;
  }
  const int srcA = ((g & 1) * 2) * 16 + c;
  const bool hi = (g >> 1) & 1;

  // ---------- prologue: issue tile-0 loads ----------
#pragma unroll
  for (int i = 0; i < 12; ++i) {
    __builtin_amdgcn_global_load_lds(
        (const __attribute__((address_space(1))) unsigned int*)(srcB +
                                                                i * 16 * kHW),
        (__attribute__((address_space(3))) unsigned int*)(wbase + i * 1024),
        16, 0, 0);
  }

#pragma unroll 1
  for (int t = 0; t < 4; ++t) {
    // wait this tile's X (also drains prior stores/weight loads; acceptable)
    asm volatile("s_waitcnt vmcnt(0)" ::: "memory");
    __builtin_amdgcn_sched_barrier(0);

    // ---------- LDS -> Xf regs (convert) ----------
    const float* const xs = (const float*)wbase;  // lds32[ch*16+px]
    bf16x8 Xf[3][2];
#pragma unroll
    for (int b = 0; b < 3; ++b)
#pragma unroll
      for (int s = 0; s < 2; ++s) {
        bf16x8 xf;
#pragma unroll
        for (int j = 0; j < 8; ++j)
          xf[j] = f2bf(xs[(b * 64 + s * 32 + g * 8 + j) * 16 + c]);
        Xf[b][s] = xf;
      }
    asm volatile("s_waitcnt lgkmcnt(0)" ::: "memory");
    __builtin_amdgcn_sched_barrier(0);

    // ---------- prefetch next tile into the same buffer ----------
    if (t < 3) {
      const float* const srcN = srcB + (t + 1) * 16;
#pragma unroll
      for (int i = 0; i < 12; ++i) {
        __builtin_amdgcn_global_load_lds(
            (const __attribute__((address_space(1))) unsigned int*)(srcN +
                                                                    i * 16 *
                                                                        kHW),
            (__attribute__((address_space(3))) unsigned int*)(wbase + i * 1024),
            16, 0, 0);
      }
    }
    __builtin_amdgcn_sched_barrier(0);

    // ---------- heads + in-register y relayout ----------
    uint2 pkA[3], pkB[3];
    bf16x8 yS0[3], yS1[3];

    head_compute<0>(wp, l, Xf, pkA);
    __builtin_amdgcn_sched_barrier(0);
    head_compute<1>(wp, l, Xf, pkB);
    __builtin_amdgcn_sched_barrier(0);
#pragma unroll
    for (int b = 0; b < 3; ++b) yS0[b] = build_frag(pkA[b], pkB[b], srcA, hi);
    __builtin_amdgcn_sched_barrier(0);
    head_compute<2>(wp, l, Xf, pkA);
    __builtin_amdgcn_sched_barrier(0);
    head_compute<3>(wp, l, Xf, pkB);
    __builtin_amdgcn_sched_barrier(0);
#pragma unroll
    for (int b = 0; b < 3; ++b) yS1[b] = build_frag(pkA[b], pkB[b], srcA, hi);

    // ---------- epilogue: proj + residual-from-Xf ----------
    float* __restrict__ outp = out + blkBase + hwW + t * 16 + c;
#pragma unroll
    for (int b = 0; b < 3; ++b) {
#pragma unroll
      for (int m = 0; m < 4; ++m) {
        const bf16x8 pA0 = wp[(24 + m * 2 + 0) * 64 + l];
        const bf16x8 pA1 = wp[(24 + m * 2 + 1) * 64 + l];
        f32x4 o =
            __builtin_amdgcn_mfma_f32_16x16x32_bf16(pA0, yS0[b], zz, 0, 0, 0);
        o = __builtin_amdgcn_mfma_f32_16x16x32_bf16(pA1, yS1[b], o, 0, 0, 0);

        union {
          bf16x8 v;
          unsigned w[4];
        } su;
        su.v = Xf[b][m >> 1];
        const int hl = ((m & 1) * 2 + (g >> 1)) * 16 + c;
        const unsigned w0 = (unsigned)__shfl((int)su.w[0], hl, 64);
        const unsigned w1 = (unsigned)__shfl((int)su.w[1], hl, 64);
        const unsigned w2 = (unsigned)__shfl((int)su.w[2], hl, 64);
        const unsigned w3 = (unsigned)__shfl((int)su.w[3], hl, 64);
        const unsigned lo = (g & 1) ? w2 : w0;   // channels j=0,1
        const unsigned hi2 = (g & 1) ? w3 : w1;  // channels j=2,3
        float res[4];
        res[0] = __uint_as_float(lo << 16);
        res[1] = __uint_as_float(lo & 0xffff0000u);
        res[2] = __uint_as_float(hi2 << 16);
        res[3] = __uint_as_float(hi2 & 0xffff0000u);

#pragma unroll
        for (int j = 0; j < 4; ++j) {
          outp[(b * 64 + m * 16 + g * 4 + j) * kHW] =
              fmaf(rv, o[j] + bias_[m][j], res[j]);
        }
      }
    }
  }
}

extern "C" void kernel_launch(void* const* d_in, const int* in_sizes, int n_in,
                              void* d_out, int out_size, void* d_ws,
                              size_t ws_size, hipStream_t stream) {
  const float* hf = (const float*)d_in[0];
  const float* Wqkv = (const float*)d_in[1];
  const float* Wproj = (const float*)d_in[2];
  const float* bproj = (const float*)d_in[3];
  const float* rscale = (const float*)d_in[4];
  float* out = (float*)d_out;
  unsigned char* wsc = (unsigned char*)d_ws;

  hipLaunchKernelGGL(pack_weights, dim3(1), dim3(256), 0, stream, Wqkv, Wproj,
                     wsc);

  const int npix = in_sizes[0] / kC;  // 131072
  const int nblocks = npix / 256;     // 512
  hipLaunchKernelGGL(hfattn_mfma14, dim3(nblocks), dim3(256), 0, stream, hf,
                     wsc, bproj, rscale, out);
}

// Round 18
// 51.970 us; speedup vs baseline: 1.4836x; 1.4836x over previous
//
#include <hip/hip_runtime.h>
#include <hip/hip_bf16.h>

// HFOnlyAttn MFMA v15: fully-coalesced cooperative READ + WRITE paths.
// Block = 64 px. 4 waves cooperatively stage X (192ch x 64px fp32) into LDS
// via 48 global_load_lds instrs; each instr = 4 channels x 256B contiguous
// (16 lanes x 16B per channel) -> 4x fewer read requests than the per-wave
// 64B-segment pattern of v2..v14. One vmcnt(0)+barrier. Readback per wave
// from lds[ch*64 + px]. Compute = v10 (heads, shuffle relayout,
// residual-from-Xf). Epilogue -> LDS out-tile (stride 68 words, aliases the
// dead X tile after a barrier) -> cooperative 256B-contiguous float4 stores.
// LDS 52224B -> 3 blocks/CU. launch_bounds(256,3).
// mfma_f32_16x16x32_bf16:  A: lane l -> row=l&15, k=(l>>4)*8+{0..7}
//                          B: lane l -> col=l&15, k=(l>>4)*8+{0..7}
//                          C: lane l -> col=l&15, row=(l>>4)*4+reg
// Relayout (v4/v10-verified): proj-B-frag(sp) lane(g,c) elem e = ych
// sp*32+g*8+e; holder lane ((g&1)*2+(e>>2))*16+c, head sp*2+(g>>1), reg e&3.
// Residual: channel b*64+m*16+g*4+j of pixel c lives in Xf[b][m>>1],
// element (g&1)*4+j, on lane ((m&1)*2+(g>>1))*16+c.

typedef __attribute__((ext_vector_type(8))) short bf16x8;
typedef __attribute__((ext_vector_type(4))) float f32x4;

constexpr int kHW = 16384;
constexpr int kC = 192;
constexpr int kOS = 68;  // out-tile stride in words (68*4=272, 16B-aligned rows)

__device__ __forceinline__ short f2bf(float f) {
  return (short)__bfloat16_as_ushort(__float2bfloat16(f));
}

// kernel0: pack Wqkv^T/Wproj^T A-fragments into ws (24 + 8 frags x 1024B).
__global__ void pack_weights(const float* __restrict__ Wqkv,
                             const float* __restrict__ Wproj,
                             unsigned char* __restrict__ wsc) {
  const int tid = threadIdx.x;
  const int wid = tid >> 6;
  const int l = tid & 63;
  const int c = l & 15;
  const int g = l >> 4;
  for (int f = wid; f < 24; f += 4) {
    const int m = f >> 1, s = f & 1;
    const int row = m * 16 + c;
    const int k0 = s * 32 + g * 8;
    bf16x8 wf;
#pragma unroll
    for (int j = 0; j < 8; ++j) wf[j] = f2bf(Wqkv[(k0 + j) * 192 + row]);
    *(bf16x8*)(wsc + f * 1024 + l * 16) = wf;
  }
  for (int f = wid; f < 8; f += 4) {
    const int m = f >> 1, s = f & 1;
    const int row = m * 16 + c;
    const int k0 = s * 32 + g * 8;
    bf16x8 wf;
#pragma unroll
    for (int j = 0; j < 8; ++j) wf[j] = f2bf(Wproj[(k0 + j) * 64 + row]);
    *(bf16x8*)(wsc + 24576 + f * 1024 + l * 16) = wf;
  }
}

// One head: q,k MFMAs -> 3x3 softmax -> v MFMAs -> y packs (3 uint2).
template <int H>
__device__ __forceinline__ void head_compute(const bf16x8* __restrict__ wp,
                                             int l, const bf16x8 (&Xf)[3][2],
                                             uint2 (&pk)[3]) {
  const f32x4 zz = {0.f, 0.f, 0.f, 0.f};
  const bf16x8 qA0 = wp[(H * 2 + 0) * 64 + l];
  const bf16x8 qA1 = wp[(H * 2 + 1) * 64 + l];
  const bf16x8 kA0 = wp[((4 + H) * 2 + 0) * 64 + l];
  const bf16x8 kA1 = wp[((4 + H) * 2 + 1) * 64 + l];
  f32x4 q[3], k[3];
#pragma unroll
  for (int b = 0; b < 3; ++b) {
    q[b] = __builtin_amdgcn_mfma_f32_16x16x32_bf16(qA0, Xf[b][0], zz, 0, 0, 0);
    q[b] = __builtin_amdgcn_mfma_f32_16x16x32_bf16(qA1, Xf[b][1], q[b], 0, 0, 0);
    k[b] = __builtin_amdgcn_mfma_f32_16x16x32_bf16(kA0, Xf[b][0], zz, 0, 0, 0);
    k[b] = __builtin_amdgcn_mfma_f32_16x16x32_bf16(kA1, Xf[b][1], k[b], 0, 0, 0);
  }
  float P[3][3];
#pragma unroll
  for (int r1 = 0; r1 < 3; ++r1) {
    float sc[3];
#pragma unroll
    for (int r2 = 0; r2 < 3; ++r2) {
      float d = q[r1][0] * k[r2][0] + q[r1][1] * k[r2][1] +
                q[r1][2] * k[r2][2] + q[r1][3] * k[r2][3];
      d += __shfl_xor(d, 16);
      d += __shfl_xor(d, 32);
      sc[r2] = d * 0.25f;
    }
    const float mx = fmaxf(sc[0], fmaxf(sc[1], sc[2]));
    const float e0 = __expf(sc[0] - mx);
    const float e1 = __expf(sc[1] - mx);
    const float e2 = __expf(sc[2] - mx);
    const float inv = 1.f / (e0 + e1 + e2);
    P[r1][0] = e0 * inv;
    P[r1][1] = e1 * inv;
    P[r1][2] = e2 * inv;
  }
  const bf16x8 vA0 = wp[((8 + H) * 2 + 0) * 64 + l];
  const bf16x8 vA1 = wp[((8 + H) * 2 + 1) * 64 + l];
  f32x4 v[3];
#pragma unroll
  for (int b = 0; b < 3; ++b) {
    v[b] = __builtin_amdgcn_mfma_f32_16x16x32_bf16(vA0, Xf[b][0], zz, 0, 0, 0);
    v[b] = __builtin_amdgcn_mfma_f32_16x16x32_bf16(vA1, Xf[b][1], v[b], 0, 0, 0);
  }
#pragma unroll
  for (int r1 = 0; r1 < 3; ++r1) {
    f32x4 y = P[r1][0] * v[0] + P[r1][1] * v[1] + P[r1][2] * v[2];
    uint2 p;
    p.x = (unsigned)(unsigned short)f2bf(y[0]) |
          ((unsigned)(unsigned short)f2bf(y[1]) << 16);
    p.y = (unsigned)(unsigned short)f2bf(y[2]) |
          ((unsigned)(unsigned short)f2bf(y[3]) << 16);
    pk[r1] = p;
  }
}

// Build proj-B-frag for K-step sp from the packs of heads (2sp, 2sp+1).
__device__ __forceinline__ bf16x8 build_frag(uint2 pkA, uint2 pkB, int srcA,
                                             bool hi) {
  uint2 a0, a1, b0, b1;
  a0.x = (unsigned)__shfl((int)pkA.x, srcA, 64);
  a0.y = (unsigned)__shfl((int)pkA.y, srcA, 64);
  a1.x = (unsigned)__shfl((int)pkB.x, srcA, 64);
  a1.y = (unsigned)__shfl((int)pkB.y, srcA, 64);
  const int srcB = srcA + 16;
  b0.x = (unsigned)__shfl((int)pkA.x, srcB, 64);
  b0.y = (unsigned)__shfl((int)pkA.y, srcB, 64);
  b1.x = (unsigned)__shfl((int)pkB.x, srcB, 64);
  b1.y = (unsigned)__shfl((int)pkB.y, srcB, 64);
  const uint2 lo = hi ? a1 : a0;
  const uint2 hi2 = hi ? b1 : b0;
  union {
    unsigned u[4];
    bf16x8 v;
  } r;
  r.u[0] = lo.x;
  r.u[1] = lo.y;
  r.u[2] = hi2.x;
  r.u[3] = hi2.y;
  return r.v;
}

__global__ __launch_bounds__(256, 3) void hfattn_mfma15(
    const float* __restrict__ hf,
    const unsigned char* __restrict__ wfr,  // packed weight frags (32KB)
    const float* __restrict__ bproj,
    const float* __restrict__ rscale,
    float* __restrict__ out) {
  // Phase 1: fp32 X tile lds[ch*64 + px] (12288 words).
  // Phase 2 (after barrier): fp32 out-tile lds[ch*68 + px] (13056 words).
  __shared__ float smem[13056];

  const int tid = threadIdx.x;
  const int wid = tid >> 6;
  const int l = tid & 63;
  const int c = l & 15;  // MFMA col (pixel slot)
  const int g = l >> 4;  // 4-lane group

  const f32x4 zz = {0.f, 0.f, 0.f, 0.f};
  const bf16x8* const wp = (const bf16x8*)wfr;

  const int pxB0 = blockIdx.x * 64;  // 2048 blocks x 64 px
  const int b8 = pxB0 >> 14;
  const int blkBase = b8 * (kC * kHW);
  const int hwT = pxB0 & (kHW - 1);  // block's first pixel

  const float rv = rscale[0];

  // ---------- cooperative coalesced X staging ----------
  // Instr idx (= wid*12+i) covers channels idx*4..idx*4+3: lane l loads 16B
  // of channel idx*4+(l>>4) at px (l&15)*4 -> each 16-lane group reads 256B
  // contiguous. HW writes LDS at smem + idx*1024 + l*16 -> lds[ch*64+px].
  {
    const int chl = l >> 4;
    const int pxl = (l & 15) * 4;
    const float* srcW = hf + blkBase + chl * kHW + hwT + pxl;
#pragma unroll
    for (int i = 0; i < 12; ++i) {
      const int idx = wid * 12 + i;
      __builtin_amdgcn_global_load_lds(
          (const __attribute__((address_space(1))) unsigned int*)(srcW +
                                                                  idx * 4 *
                                                                      kHW),
          (__attribute__((address_space(3))) unsigned int*)((char*)smem +
                                                            idx * 1024),
          16, 0, 0);
    }
  }

  // bias while loads fly
  float bias_[4][4];
#pragma unroll
  for (int m = 0; m < 4; ++m) {
    const float4 bj = *(const float4*)(bproj + m * 16 + g * 4);
    bias_[m][0] = bj.x;
    bias_[m][1] = bj.y;
    bias_[m][2] = bj.z;
    bias_[m][3] = bj.w;
  }

  asm volatile("s_waitcnt vmcnt(0)" ::: "memory");
  __syncthreads();  // whole X tile visible

  // ---------- readback + convert: this wave's 16-px window ----------
  bf16x8 Xf[3][2];
#pragma unroll
  for (int b = 0; b < 3; ++b)
#pragma unroll
    for (int s = 0; s < 2; ++s) {
      bf16x8 xf;
#pragma unroll
      for (int j = 0; j < 8; ++j)
        xf[j] = f2bf(smem[(b * 64 + s * 32 + g * 8 + j) * 64 + wid * 16 + c]);
      Xf[b][s] = xf;
    }
  __syncthreads();  // all waves done reading X; LDS can be reused as out-tile

  // ---------- heads + in-register y relayout (v10) ----------
  const int srcA = ((g & 1) * 2) * 16 + c;
  const bool hi = (g >> 1) & 1;

  uint2 pkA[3], pkB[3];
  bf16x8 yS0[3], yS1[3];

  head_compute<0>(wp, l, Xf, pkA);
  __builtin_amdgcn_sched_barrier(0);
  head_compute<1>(wp, l, Xf, pkB);
  __builtin_amdgcn_sched_barrier(0);
#pragma unroll
  for (int b = 0; b < 3; ++b) yS0[b] = build_frag(pkA[b], pkB[b], srcA, hi);
  __builtin_amdgcn_sched_barrier(0);
  head_compute<2>(wp, l, Xf, pkA);
  __builtin_amdgcn_sched_barrier(0);
  head_compute<3>(wp, l, Xf, pkB);
  __builtin_amdgcn_sched_barrier(0);
#pragma unroll
  for (int b = 0; b < 3; ++b) yS1[b] = build_frag(pkA[b], pkB[b], srcA, hi);

  // ---------- epilogue: proj + residual-from-Xf -> LDS out-tile ----------
#pragma unroll
  for (int b = 0; b < 3; ++b) {
#pragma unroll
    for (int m = 0; m < 4; ++m) {
      const bf16x8 pA0 = wp[(24 + m * 2 + 0) * 64 + l];
      const bf16x8 pA1 = wp[(24 + m * 2 + 1) * 64 + l];
      f32x4 o = __builtin_amdgcn_mfma_f32_16x16x32_bf16(pA0, yS0[b], zz, 0, 0, 0);
      o = __builtin_amdgcn_mfma_f32_16x16x32_bf16(pA1, yS1[b], o, 0, 0, 0);

      // residual from Xf via wave shuffles (all transient)
      union {
        bf16x8 v;
        unsigned w[4];
      } su;
      su.v = Xf[b][m >> 1];
      const int hl = ((m & 1) * 2 + (g >> 1)) * 16 + c;
      const unsigned w0 = (unsigned)__shfl((int)su.w[0], hl, 64);
      const unsigned w1 = (unsigned)__shfl((int)su.w[1], hl, 64);
      const unsigned w2 = (unsigned)__shfl((int)su.w[2], hl, 64);
      const unsigned w3 = (unsigned)__shfl((int)su.w[3], hl, 64);
      const unsigned lo = (g & 1) ? w2 : w0;   // channels j=0,1
      const unsigned hi2 = (g & 1) ? w3 : w1;  // channels j=2,3
      float res[4];
      res[0] = __uint_as_float(lo << 16);
      res[1] = __uint_as_float(lo & 0xffff0000u);
      res[2] = __uint_as_float(hi2 << 16);
      res[3] = __uint_as_float(hi2 & 0xffff0000u);

#pragma unroll
      for (int j = 0; j < 4; ++j) {
        const int ch = b * 64 + m * 16 + g * 4 + j;
        smem[ch * kOS + wid * 16 + c] = fmaf(rv, o[j] + bias_[m][j], res[j]);
      }
    }
  }

  __syncthreads();

  // ---------- cooperative coalesced store: 256B contiguous per channel ----
  // Wave wid owns channels [wid*48, wid*48+48). Instr i: lane l stores a
  // float4 (4 px) of channel wid*48 + i*4 + (l>>4) at px (l&15)*4.
  {
    const int chl = l >> 4;
    const int pxl = (l & 15) * 4;
    float* __restrict__ outp = out + blkBase + hwT + pxl;
#pragma unroll
    for (int i = 0; i < 12; ++i) {
      const int ch = wid * 48 + i * 4 + chl;
      const float4 v = *(const float4*)&smem[ch * kOS + pxl];
      *(float4*)(outp + ch * kHW) = v;
    }
  }
}

extern "C" void kernel_launch(void* const* d_in, const int* in_sizes, int n_in,
                              void* d_out, int out_size, void* d_ws,
                              size_t ws_size, hipStream_t stream) {
  const float* hf = (const float*)d_in[0];
  const float* Wqkv = (const float*)d_in[1];
  const float* Wproj = (const float*)d_in[2];
  const float* bproj = (const float*)d_in[3];
  const float* rscale = (const float*)d_in[4];
  float* out = (float*)d_out;
  unsigned char* wsc = (unsigned char*)d_ws;

  hipLaunchKernelGGL(pack_weights, dim3(1), dim3(256), 0, stream, Wqkv, Wproj,
                     wsc);

  const int npix = in_sizes[0] / kC;  // 131072
  const int nblocks = npix / 64;      // 2048
  hipLaunchKernelGGL(hfattn_mfma15, dim3(nblocks), dim3(256), 0, stream, hf,
                     wsc, bproj, rscale, out);
}

// Round 19
// 48.511 us; speedup vs baseline: 1.5894x; 1.0713x over previous
//
#include <hip/hip_runtime.h>

// HFOnlyAttn MFMA v10 (CHAMPION, 48.5us @ R12) — resubmitted to lock in.
// Weight frags staged to LDS (32KB, once per block, global_load_lds + 1
// barrier); y-relayout via verified in-register shuffles (no y-LDS).
// 48-deep X-load staging, sched_barrier-fenced; residual reconstructed from
// Xf via shuffles (no VMEM re-read). LDS 32KB -> 4 blocks/CU at
// launch_bounds(256,4).
// Evidence base (R2-R18): 8 structural variants all pin at 48.5-52us with
// clean counters; traffic is algorithmic-minimal (FETCH~49MB L3-resident,
// WRITE~98MB = output exactly once). Plateau is the memory system's
// effective rate (~3 TB/s) for this 64B-per-channel scatter pattern;
// occupancy, staging depth, and coalescing all proven non-binding.
// mfma_f32_16x16x32_bf16:  A: lane l -> row=l&15, k=(l>>4)*8+{0..7}
//                          B: lane l -> col=l&15, k=(l>>4)*8+{0..7}
//                          C: lane l -> col=l&15, row=(l>>4)*4+reg
// Relayout (v4-verified): proj-B-frag(sp) lane(g,c) elem e = ych sp*32+g*8+e;
// holder lane ((g&1)*2+(e>>2))*16+c, head sp*2+(g>>1), reg e&3.
// Residual: channel b*64+m*16+g*4+j of pixel c lives in Xf[b][m>>1],
// element (g&1)*4+j, on lane ((m&1)*2+(g>>1))*16+c.

typedef __attribute__((ext_vector_type(8))) short bf16x8;
typedef __attribute__((ext_vector_type(4))) float f32x4;

constexpr int kHW = 16384;
constexpr int kC = 192;

__device__ __forceinline__ unsigned short f2bf(float f) {
  unsigned int u = __float_as_uint(f);
  return (unsigned short)((u + 0x7fffu + ((u >> 16) & 1u)) >> 16);  // RNE
}

// kernel0: pack Wqkv^T/Wproj^T A-fragments into ws (24 + 8 frags x 1024B).
__global__ void pack_weights(const float* __restrict__ Wqkv,
                             const float* __restrict__ Wproj,
                             unsigned char* __restrict__ wsc) {
  const int tid = threadIdx.x;
  const int wid = tid >> 6;
  const int l = tid & 63;
  const int c = l & 15;
  const int g = l >> 4;
  for (int f = wid; f < 24; f += 4) {
    const int m = f >> 1, s = f & 1;
    const int row = m * 16 + c;
    const int k0 = s * 32 + g * 8;
    bf16x8 wf;
#pragma unroll
    for (int j = 0; j < 8; ++j) wf[j] = (short)f2bf(Wqkv[(k0 + j) * 192 + row]);
    *(bf16x8*)(wsc + f * 1024 + l * 16) = wf;
  }
  for (int f = wid; f < 8; f += 4) {
    const int m = f >> 1, s = f & 1;
    const int row = m * 16 + c;
    const int k0 = s * 32 + g * 8;
    bf16x8 wf;
#pragma unroll
    for (int j = 0; j < 8; ++j) wf[j] = (short)f2bf(Wproj[(k0 + j) * 64 + row]);
    *(bf16x8*)(wsc + 24576 + f * 1024 + l * 16) = wf;
  }
}

// One head: q,k MFMAs -> 3x3 softmax -> v MFMAs -> y packs (3 uint2).
// Weights read from LDS (ds_read_b128, lgkmcnt-pipelined).
template <int H>
__device__ __forceinline__ void head_compute(const char* wl, int l,
                                             const bf16x8 (&Xf)[3][2],
                                             uint2 (&pk)[3]) {
  const f32x4 zz = {0.f, 0.f, 0.f, 0.f};
  const bf16x8 qA0 = *(const bf16x8*)(wl + (H * 2 + 0) * 1024 + l * 16);
  const bf16x8 qA1 = *(const bf16x8*)(wl + (H * 2 + 1) * 1024 + l * 16);
  const bf16x8 kA0 = *(const bf16x8*)(wl + ((4 + H) * 2 + 0) * 1024 + l * 16);
  const bf16x8 kA1 = *(const bf16x8*)(wl + ((4 + H) * 2 + 1) * 1024 + l * 16);
  f32x4 q[3], k[3];
#pragma unroll
  for (int b = 0; b < 3; ++b) {
    q[b] = __builtin_amdgcn_mfma_f32_16x16x32_bf16(qA0, Xf[b][0], zz, 0, 0, 0);
    q[b] = __builtin_amdgcn_mfma_f32_16x16x32_bf16(qA1, Xf[b][1], q[b], 0, 0, 0);
    k[b] = __builtin_amdgcn_mfma_f32_16x16x32_bf16(kA0, Xf[b][0], zz, 0, 0, 0);
    k[b] = __builtin_amdgcn_mfma_f32_16x16x32_bf16(kA1, Xf[b][1], k[b], 0, 0, 0);
  }
  float P[3][3];
#pragma unroll
  for (int r1 = 0; r1 < 3; ++r1) {
    float sc[3];
#pragma unroll
    for (int r2 = 0; r2 < 3; ++r2) {
      float d = q[r1][0] * k[r2][0] + q[r1][1] * k[r2][1] +
                q[r1][2] * k[r2][2] + q[r1][3] * k[r2][3];
      d += __shfl_xor(d, 16);
      d += __shfl_xor(d, 32);
      sc[r2] = d * 0.25f;
    }
    const float mx = fmaxf(sc[0], fmaxf(sc[1], sc[2]));
    const float e0 = __expf(sc[0] - mx);
    const float e1 = __expf(sc[1] - mx);
    const float e2 = __expf(sc[2] - mx);
    const float inv = 1.f / (e0 + e1 + e2);
    P[r1][0] = e0 * inv;
    P[r1][1] = e1 * inv;
    P[r1][2] = e2 * inv;
  }
  const bf16x8 vA0 = *(const bf16x8*)(wl + ((8 + H) * 2 + 0) * 1024 + l * 16);
  const bf16x8 vA1 = *(const bf16x8*)(wl + ((8 + H) * 2 + 1) * 1024 + l * 16);
  f32x4 v[3];
#pragma unroll
  for (int b = 0; b < 3; ++b) {
    v[b] = __builtin_amdgcn_mfma_f32_16x16x32_bf16(vA0, Xf[b][0], zz, 0, 0, 0);
    v[b] = __builtin_amdgcn_mfma_f32_16x16x32_bf16(vA1, Xf[b][1], v[b], 0, 0, 0);
  }
#pragma unroll
  for (int r1 = 0; r1 < 3; ++r1) {
    f32x4 y = P[r1][0] * v[0] + P[r1][1] * v[1] + P[r1][2] * v[2];
    uint2 p;
    p.x = (unsigned)f2bf(y[0]) | ((unsigned)f2bf(y[1]) << 16);
    p.y = (unsigned)f2bf(y[2]) | ((unsigned)f2bf(y[3]) << 16);
    pk[r1] = p;
  }
}

// Build proj-B-frag for K-step sp from the packs of heads (2sp, 2sp+1).
__device__ __forceinline__ bf16x8 build_frag(uint2 pkA, uint2 pkB, int srcA,
                                             bool hi) {
  uint2 a0, a1, b0, b1;
  a0.x = (unsigned)__shfl((int)pkA.x, srcA, 64);
  a0.y = (unsigned)__shfl((int)pkA.y, srcA, 64);
  a1.x = (unsigned)__shfl((int)pkB.x, srcA, 64);
  a1.y = (unsigned)__shfl((int)pkB.y, srcA, 64);
  const int srcB = srcA + 16;
  b0.x = (unsigned)__shfl((int)pkA.x, srcB, 64);
  b0.y = (unsigned)__shfl((int)pkA.y, srcB, 64);
  b1.x = (unsigned)__shfl((int)pkB.x, srcB, 64);
  b1.y = (unsigned)__shfl((int)pkB.y, srcB, 64);
  const uint2 lo = hi ? a1 : a0;
  const uint2 hi2 = hi ? b1 : b0;
  union {
    unsigned u[4];
    bf16x8 v;
  } r;
  r.u[0] = lo.x;
  r.u[1] = lo.y;
  r.u[2] = hi2.x;
  r.u[3] = hi2.y;
  return r.v;
}

__global__ __launch_bounds__(256, 4) void hfattn_mfma10(
    const float* __restrict__ hf,
    const unsigned char* __restrict__ wfr,  // packed weight frags (32KB)
    const float* __restrict__ bproj,
    const float* __restrict__ rscale,
    float* __restrict__ out) {
  // LDS: the 32KB weight-fragment table, staged once per block.
  __shared__ char wlds[32768];

  const int tid = threadIdx.x;
  const int wid = tid >> 6;
  const int l = tid & 63;
  const int c = l & 15;  // MFMA col (pixel slot)
  const int g = l >> 4;  // 4-lane group

  const f32x4 zz = {0.f, 0.f, 0.f, 0.f};

  const int pxB = blockIdx.x * 64 + wid * 16;  // 2048 blocks x 64 px
  const int b8 = pxB >> 14;
  const int blkBase = b8 * (kC * kHW);
  const int hw = (pxB & (kHW - 1)) + c;
  const float* __restrict__ hfp = hf + blkBase + hw;
  float* __restrict__ outp = out + blkBase + hw;

  const float rv = rscale[0];

  // ---------- stage weight table into LDS (wave w: bytes w*8K..w*8K+8K) ----
#pragma unroll
  for (int i = 0; i < 8; ++i) {
    __builtin_amdgcn_global_load_lds(
        (const __attribute__((address_space(1))) unsigned int*)(wfr +
                                                                wid * 8192 +
                                                                i * 1024 +
                                                                l * 16),
        (__attribute__((address_space(3))) unsigned int*)(wlds + wid * 8192 +
                                                          i * 1024),
        16, 0, 0);
  }

  // ---------- issue ALL 48 X loads, fence, convert ----------
  float xr[3][2][8];
#pragma unroll
  for (int b = 0; b < 3; ++b)
#pragma unroll
    for (int s = 0; s < 2; ++s)
#pragma unroll
      for (int j = 0; j < 8; ++j)
        xr[b][s][j] = hfp[(b * 64 + s * 32 + g * 8 + j) * kHW];
  __builtin_amdgcn_sched_barrier(0);  // all loads issue before any convert

  bf16x8 Xf[3][2];
#pragma unroll
  for (int b = 0; b < 3; ++b)
#pragma unroll
    for (int s = 0; s < 2; ++s) {
      bf16x8 xf;
#pragma unroll
      for (int j = 0; j < 8; ++j) xf[j] = (short)f2bf(xr[b][s][j]);
      Xf[b][s] = xf;
    }

  // weight table fully in LDS before any wave reads it
  asm volatile("s_waitcnt vmcnt(0)" ::: "memory");
  __syncthreads();

  // ---------- heads + in-register y relayout ----------
  const int srcA = ((g & 1) * 2) * 16 + c;
  const bool hi = (g >> 1) & 1;

  uint2 pkA[3], pkB[3];
  bf16x8 yS0[3], yS1[3];

  head_compute<0>(wlds, l, Xf, pkA);
  __builtin_amdgcn_sched_barrier(0);
  head_compute<1>(wlds, l, Xf, pkB);
  __builtin_amdgcn_sched_barrier(0);
#pragma unroll
  for (int b = 0; b < 3; ++b) yS0[b] = build_frag(pkA[b], pkB[b], srcA, hi);
  __builtin_amdgcn_sched_barrier(0);
  head_compute<2>(wlds, l, Xf, pkA);
  __builtin_amdgcn_sched_barrier(0);
  head_compute<3>(wlds, l, Xf, pkB);
  __builtin_amdgcn_sched_barrier(0);
#pragma unroll
  for (int b = 0; b < 3; ++b) yS1[b] = build_frag(pkA[b], pkB[b], srcA, hi);

  // ---------- epilogue: proj + residual-from-Xf ----------
  float bias_[4][4];
#pragma unroll
  for (int m = 0; m < 4; ++m) {
    const float4 bj = *(const float4*)(bproj + m * 16 + g * 4);
    bias_[m][0] = bj.x;
    bias_[m][1] = bj.y;
    bias_[m][2] = bj.z;
    bias_[m][3] = bj.w;
  }

#pragma unroll
  for (int b = 0; b < 3; ++b) {
#pragma unroll
    for (int m = 0; m < 4; ++m) {
      const bf16x8 pA0 =
          *(const bf16x8*)(wlds + (24 + m * 2 + 0) * 1024 + l * 16);
      const bf16x8 pA1 =
          *(const bf16x8*)(wlds + (24 + m * 2 + 1) * 1024 + l * 16);
      f32x4 o = __builtin_amdgcn_mfma_f32_16x16x32_bf16(pA0, yS0[b], zz, 0, 0, 0);
      o = __builtin_amdgcn_mfma_f32_16x16x32_bf16(pA1, yS1[b], o, 0, 0, 0);

      // residual from Xf via wave shuffles (all transient)
      union {
        bf16x8 v;
        unsigned u[4];
      } su;
      su.v = Xf[b][m >> 1];
      const int hl = ((m & 1) * 2 + (g >> 1)) * 16 + c;
      const unsigned w0 = (unsigned)__shfl((int)su.u[0], hl, 64);
      const unsigned w1 = (unsigned)__shfl((int)su.u[1], hl, 64);
      const unsigned w2 = (unsigned)__shfl((int)su.u[2], hl, 64);
      const unsigned w3 = (unsigned)__shfl((int)su.u[3], hl, 64);
      const unsigned lo = (g & 1) ? w2 : w0;  // channels j=0,1
      const unsigned hi2 = (g & 1) ? w3 : w1;  // channels j=2,3
      float res[4];
      res[0] = __uint_as_float(lo << 16);
      res[1] = __uint_as_float(lo & 0xffff0000u);
      res[2] = __uint_as_float(hi2 << 16);
      res[3] = __uint_as_float(hi2 & 0xffff0000u);

#pragma unroll
      for (int j = 0; j < 4; ++j) {
        outp[(b * 64 + m * 16 + g * 4 + j) * kHW] =
            fmaf(rv, o[j] + bias_[m][j], res[j]);
      }
    }
  }
}

extern "C" void kernel_launch(void* const* d_in, const int* in_sizes, int n_in,
                              void* d_out, int out_size, void* d_ws,
                              size_t ws_size, hipStream_t stream) {
  const float* hf = (const float*)d_in[0];
  const float* Wqkv = (const float*)d_in[1];
  const float* Wproj = (const float*)d_in[2];
  const float* bproj = (const float*)d_in[3];
  const float* rscale = (const float*)d_in[4];
  float* out = (float*)d_out;
  unsigned char* wsc = (unsigned char*)d_ws;

  hipLaunchKernelGGL(pack_weights, dim3(1), dim3(256), 0, stream, Wqkv, Wproj,
                     wsc);

  const int npix = in_sizes[0] / kC;  // 131072
  const int nblocks = npix / 64;      // 2048
  hipLaunchKernelGGL(hfattn_mfma10, dim3(nblocks), dim3(256), 0, stream, hf,
                     wsc, bproj, rscale, out);
}